// Round 2
// baseline (2388.913 us; speedup 1.0000x reference)
//
#include <hip/hip_runtime.h>
#include <stdint.h>

typedef unsigned short u16;
typedef __bf16 bf16x8 __attribute__((ext_vector_type(8)));
typedef float f32x4 __attribute__((ext_vector_type(4)));

#define B_ 4
#define S_ 2048
#define H_ 16
#define TOK (B_*S_)

__device__ __forceinline__ u16 f32_bf16(float f) {
    union { float f; unsigned int u; } x; x.f = f;
    return (u16)((x.u + 0x7fffu + ((x.u >> 16) & 1u)) >> 16);
}
__device__ __forceinline__ float bf2f(u16 v) {
    union { unsigned int u; float f; } x; x.u = ((unsigned int)v) << 16; return x.f;
}
__device__ __forceinline__ void gld_lds16(const u16* g, u16* lds) {
    __builtin_amdgcn_global_load_lds(
        (const __attribute__((address_space(1))) unsigned int*)g,
        (__attribute__((address_space(3))) unsigned int*)lds, 16, 0, 0);
}

__global__ void fill_sentinel(float* o, int n) {
    int i = blockIdx.x * 256 + threadIdx.x;
    if (i < n) o[i] = 12345.0f;
}

// ---------------- weight transpose + f32->bf16: in [K,N] f32 -> out [Npad,K] bf16 ----------------
__global__ __launch_bounds__(256) void transpose_f32_bf16(const float* __restrict__ in, u16* __restrict__ out,
                                                          int K, int N, int Npad) {
    __shared__ float t[32][33];
    int nb = blockIdx.x * 32, kb = blockIdx.y * 32;
    int c = threadIdx.x & 31, r = threadIdx.x >> 5;
#pragma unroll
    for (int i = 0; i < 4; ++i) {
        int kk = kb + r + i * 8, nn = nb + c;
        t[r + i * 8][c] = (kk < K && nn < N) ? in[(size_t)kk * N + nn] : 0.f;
    }
    __syncthreads();
#pragma unroll
    for (int i = 0; i < 4; ++i) {
        int no = nb + r + i * 8, ko = kb + c;
        if (no < Npad && ko < K) out[(size_t)no * K + ko] = f32_bf16(t[c][r + i * 8]);
    }
}

// ---------------- rmsnorm: f32 in -> bf16 out ----------------
__global__ __launch_bounds__(256) void rmsnorm_f32(const float* __restrict__ in, const float* __restrict__ sc,
                                                   u16* __restrict__ out, int N) {
    int row = blockIdx.x;
    const float* x = in + (size_t)row * N;
    float ss = 0.f;
    for (int c = threadIdx.x * 4; c < N; c += 1024) {
        float4 v = *(const float4*)(x + c);
        ss += v.x * v.x + v.y * v.y + v.z * v.z + v.w * v.w;
    }
#pragma unroll
    for (int off = 32; off; off >>= 1) ss += __shfl_down(ss, off);
    __shared__ float red[4];
    if ((threadIdx.x & 63) == 0) red[threadIdx.x >> 6] = ss;
    __syncthreads();
    float rs = rsqrtf((red[0] + red[1] + red[2] + red[3]) / (float)N + 1e-6f);
    for (int c = threadIdx.x * 4; c < N; c += 1024) {
        float4 v = *(const float4*)(x + c);
        float4 s4 = *(const float4*)(sc + c);
        ushort4 ov;
        ov.x = f32_bf16(v.x * rs * s4.x);
        ov.y = f32_bf16(v.y * rs * s4.y);
        ov.z = f32_bf16(v.z * rs * s4.z);
        ov.w = f32_bf16(v.w * rs * s4.w);
        *(ushort4*)&out[(size_t)row * N + c] = ov;
    }
}

// ---------------- rmsnorm: bf16 in -> bf16 out (in-place safe) ----------------
__global__ __launch_bounds__(256) void rmsnorm_bf16(const u16* __restrict__ in, const float* __restrict__ sc,
                                                    u16* __restrict__ out, int N) {
    int row = blockIdx.x;
    const u16* x = in + (size_t)row * N;
    float ss = 0.f;
    for (int c = threadIdx.x * 8; c < N; c += 2048) {
        ushort4 v0 = *(const ushort4*)(x + c);
        ushort4 v1 = *(const ushort4*)(x + c + 4);
        float f0 = bf2f(v0.x), f1 = bf2f(v0.y), f2 = bf2f(v0.z), f3 = bf2f(v0.w);
        float f4 = bf2f(v1.x), f5 = bf2f(v1.y), f6 = bf2f(v1.z), f7 = bf2f(v1.w);
        ss += f0*f0 + f1*f1 + f2*f2 + f3*f3 + f4*f4 + f5*f5 + f6*f6 + f7*f7;
    }
#pragma unroll
    for (int off = 32; off; off >>= 1) ss += __shfl_down(ss, off);
    __shared__ float red[4];
    if ((threadIdx.x & 63) == 0) red[threadIdx.x >> 6] = ss;
    __syncthreads();
    float rs = rsqrtf((red[0] + red[1] + red[2] + red[3]) / (float)N + 1e-6f);
    for (int c = threadIdx.x * 8; c < N; c += 2048) {
        ushort4 v0 = *(const ushort4*)(x + c);
        ushort4 v1 = *(const ushort4*)(x + c + 4);
        ushort4 o0, o1;
        o0.x = f32_bf16(bf2f(v0.x) * rs * sc[c + 0]);
        o0.y = f32_bf16(bf2f(v0.y) * rs * sc[c + 1]);
        o0.z = f32_bf16(bf2f(v0.z) * rs * sc[c + 2]);
        o0.w = f32_bf16(bf2f(v0.w) * rs * sc[c + 3]);
        o1.x = f32_bf16(bf2f(v1.x) * rs * sc[c + 4]);
        o1.y = f32_bf16(bf2f(v1.y) * rs * sc[c + 5]);
        o1.z = f32_bf16(bf2f(v1.z) * rs * sc[c + 6]);
        o1.w = f32_bf16(bf2f(v1.w) * rs * sc[c + 7]);
        *(ushort4*)&out[(size_t)row * N + c] = o0;
        *(ushort4*)&out[(size_t)row * N + c + 4] = o1;
    }
}

// ---------------- kv post: bf16 [tok,640]; rmsnorm cols 0..511 -> c_kv; rope cols 512..575 -> krope ----------------
__global__ __launch_bounds__(128) void kv_post(const u16* __restrict__ kv, const float* __restrict__ scale,
                                               const int* __restrict__ pos, u16* __restrict__ ckv,
                                               u16* __restrict__ kr) {
    int row = blockIdx.x;
    const u16* x = kv + (size_t)row * 640;
    int c = threadIdx.x * 4;
    ushort4 v = *(const ushort4*)(x + c);
    float f0 = bf2f(v.x), f1 = bf2f(v.y), f2 = bf2f(v.z), f3 = bf2f(v.w);
    float ss = f0*f0 + f1*f1 + f2*f2 + f3*f3;
#pragma unroll
    for (int off = 32; off; off >>= 1) ss += __shfl_down(ss, off);
    __shared__ float red[2];
    if ((threadIdx.x & 63) == 0) red[threadIdx.x >> 6] = ss;
    __syncthreads();
    float rs = rsqrtf((red[0] + red[1]) * (1.f / 512.f) + 1e-6f);
    float4 s4 = *(const float4*)(scale + c);
    ushort4 ov;
    ov.x = f32_bf16(f0 * rs * s4.x);
    ov.y = f32_bf16(f1 * rs * s4.y);
    ov.z = f32_bf16(f2 * rs * s4.z);
    ov.w = f32_bf16(f3 * rs * s4.w);
    *(ushort4*)&ckv[(size_t)row * 512 + c] = ov;
    if (threadIdx.x < 32) {
        int i = threadIdx.x;
        float x1 = bf2f(x[512 + i]), x2 = bf2f(x[544 + i]);
        float inv = expf(-(float)(2 * i) * (1.f / 64.f) * 9.2103403719761836f);
        float ang = (float)pos[row] * inv;
        float sn, cs; sincosf(ang, &sn, &cs);
        kr[(size_t)row * 64 + i]      = f32_bf16(x1 * cs - x2 * sn);
        kr[(size_t)row * 64 + 32 + i] = f32_bf16(x2 * cs + x1 * sn);
    }
}

// ---------------- q rope in-place on bf16 [tok,16,192], dims 128..191 ----------------
__global__ __launch_bounds__(64) void q_rope_inplace(u16* __restrict__ q, const int* __restrict__ pos) {
    int token = blockIdx.x, h = blockIdx.y;
    u16* p = q + ((size_t)token * 16 + h) * 192;
    int t = threadIdx.x, i = t & 31;
    float x1 = bf2f(p[128 + i]), x2 = bf2f(p[160 + i]);
    float inv = expf(-(float)(2 * i) * (1.f / 64.f) * 9.2103403719761836f);
    float ang = (float)pos[token] * inv;
    float sn, cs; sincosf(ang, &sn, &cs);
    float val = (t < 32) ? (x1 * cs - x2 * sn) : (x2 * cs + x1 * sn);
    p[128 + t] = f32_bf16(val);   // all lanes' loads precede the wave's store
}

// ---------------- kv build: bf16 kvu chunk [2048,16,256] + krope -> swizzled K tiles / V^T tiles ----------------
__global__ __launch_bounds__(320) void kv_build(const u16* __restrict__ kvu, const u16* __restrict__ kr,
                                                u16* __restrict__ kf, u16* __restrict__ vf, int tok0) {
    int local = blockIdx.x, h = blockIdx.y;
    int token = tok0 + local;
    int b = token >> 11, s = token & 2047;
    int bh = b * 16 + h;
    int tile = s >> 6, ki = s & 63;
    const u16* u = kvu + ((size_t)local * 16 + h) * 256;
    int t = threadIdx.x;
    if (t < 192) {
        u16 val = (t < 128) ? u[t] : kr[(size_t)token * 64 + (t - 128)];
        int byte = (ki * 384 + t * 2) ^ ((ki & 7) << 4);
        kf[(size_t)bh * (S_ * 192) + (size_t)tile * 12288 + (byte >> 1)] = val;
    } else {
        int dv = t - 192;
        u16 val = u[128 + dv];
        int byte = (dv * 128 + ki * 2) ^ ((dv & 7) << 4);
        vf[(size_t)bh * (S_ * 128) + (size_t)tile * 8192 + (byte >> 1)] = val;
    }
}

// ---------------- GEMM: A [M,K] bf16 @ Bt [N,K] bf16 ; EPI 0: bf16 out, 1: bf16 out + f32 resid, 2: f32 out + bf16 resid ----------------
template<int EPI>
__global__ __launch_bounds__(256) void gemm_bt(const u16* __restrict__ A, const u16* __restrict__ Bt,
                                               void* __restrict__ Cv, const void* __restrict__ Rv,
                                               int M, int N, int K) {
    __shared__ u16 As[128 * 32];
    __shared__ u16 Bs[128 * 32];
    const int l = threadIdx.x & 63, w = threadIdx.x >> 6;
    const int wr = w >> 1, wc = w & 1;
    const int m0 = blockIdx.y * 128, n0 = blockIdx.x * 128;
    const int lm = l & 15, lg = l >> 4;
    const int srow = l >> 2, sk = (l & 3) * 8;
    f32x4 acc[4][4] = {};
    for (int k0 = 0; k0 < K; k0 += 32) {
#pragma unroll
        for (int i = 0; i < 2; ++i) {
            int c = w * 2 + i;
            gld_lds16(A  + (size_t)(m0 + c * 16 + srow) * K + k0 + sk, &As[c * 512]);
            gld_lds16(Bt + (size_t)(n0 + c * 16 + srow) * K + k0 + sk, &Bs[c * 512]);
        }
        __syncthreads();
        bf16x8 a[4], b[4];
#pragma unroll
        for (int m = 0; m < 4; ++m) a[m] = *(const bf16x8*)&As[(wr * 64 + m * 16 + lm) * 32 + lg * 8];
#pragma unroll
        for (int n = 0; n < 4; ++n) b[n] = *(const bf16x8*)&Bs[(wc * 64 + n * 16 + lm) * 32 + lg * 8];
#pragma unroll
        for (int m = 0; m < 4; ++m)
#pragma unroll
            for (int n = 0; n < 4; ++n)
                acc[m][n] = __builtin_amdgcn_mfma_f32_16x16x32_bf16(a[m], b[n], acc[m][n], 0, 0, 0);
        __syncthreads();
    }
#pragma unroll
    for (int m = 0; m < 4; ++m) {
#pragma unroll
        for (int j = 0; j < 4; ++j) {
            int row = m0 + wr * 64 + m * 16 + lg * 4 + j;
            size_t base = (size_t)row * N + n0 + wc * 64;
#pragma unroll
            for (int n = 0; n < 4; ++n) {
                size_t idx = base + n * 16 + lm;
                float v = acc[m][n][j];
                if (EPI == 0) {
                    ((u16*)Cv)[idx] = f32_bf16(v);
                } else if (EPI == 1) {
                    ((u16*)Cv)[idx] = f32_bf16(v + ((const float*)Rv)[idx]);
                } else {
                    ((float*)Cv)[idx] = v + bf2f(((const u16*)Rv)[idx]);
                }
            }
        }
    }
}

// ---------------- fused MLP GEMM: silu(A@B0^T)*(A@B1^T) -> bf16 ----------------
__global__ __launch_bounds__(256, 2) void gemm_mlp(const u16* __restrict__ A, const u16* __restrict__ B0t,
                                                   const u16* __restrict__ B1t, u16* __restrict__ actout,
                                                   int M, int N, int K) {
    __shared__ u16 As[128 * 32];
    __shared__ u16 B0s[128 * 32];
    __shared__ u16 B1s[128 * 32];
    const int l = threadIdx.x & 63, w = threadIdx.x >> 6;
    const int wr = w >> 1, wc = w & 1;
    const int m0 = blockIdx.y * 128, n0 = blockIdx.x * 128;
    const int lm = l & 15, lg = l >> 4;
    const int srow = l >> 2, sk = (l & 3) * 8;
    f32x4 a0[4][4] = {}, a1[4][4] = {};
    for (int k0 = 0; k0 < K; k0 += 32) {
#pragma unroll
        for (int i = 0; i < 2; ++i) {
            int c = w * 2 + i;
            gld_lds16(A   + (size_t)(m0 + c * 16 + srow) * K + k0 + sk, &As[c * 512]);
            gld_lds16(B0t + (size_t)(n0 + c * 16 + srow) * K + k0 + sk, &B0s[c * 512]);
            gld_lds16(B1t + (size_t)(n0 + c * 16 + srow) * K + k0 + sk, &B1s[c * 512]);
        }
        __syncthreads();
        bf16x8 a[4], b0[4], b1[4];
#pragma unroll
        for (int m = 0; m < 4; ++m) a[m] = *(const bf16x8*)&As[(wr * 64 + m * 16 + lm) * 32 + lg * 8];
#pragma unroll
        for (int n = 0; n < 4; ++n) {
            b0[n] = *(const bf16x8*)&B0s[(wc * 64 + n * 16 + lm) * 32 + lg * 8];
            b1[n] = *(const bf16x8*)&B1s[(wc * 64 + n * 16 + lm) * 32 + lg * 8];
        }
#pragma unroll
        for (int m = 0; m < 4; ++m)
#pragma unroll
            for (int n = 0; n < 4; ++n) {
                a0[m][n] = __builtin_amdgcn_mfma_f32_16x16x32_bf16(a[m], b0[n], a0[m][n], 0, 0, 0);
                a1[m][n] = __builtin_amdgcn_mfma_f32_16x16x32_bf16(a[m], b1[n], a1[m][n], 0, 0, 0);
            }
        __syncthreads();
    }
#pragma unroll
    for (int m = 0; m < 4; ++m) {
#pragma unroll
        for (int j = 0; j < 4; ++j) {
            int row = m0 + wr * 64 + m * 16 + lg * 4 + j;
            size_t base = (size_t)row * N + n0 + wc * 64;
#pragma unroll
            for (int n = 0; n < 4; ++n) {
                float x = a0[m][n][j], y = a1[m][n][j];
                float sl = x / (1.f + expf(-x));
                actout[base + n * 16 + lm] = f32_bf16(sl * y);
            }
        }
    }
}

// ---------------- flash attention, causal; Q [tok,16,192]; K/V pre-swizzled tiles ----------------
__global__ __launch_bounds__(256) void attn_fwd(const u16* __restrict__ qf, const u16* __restrict__ kfs,
                                                const u16* __restrict__ vfs, u16* __restrict__ attn) {
    __shared__ u16 Ks[64 * 192];
    __shared__ u16 Vs[128 * 64];
    __shared__ u16 Ps[4][1024];
    const int qb = blockIdx.x;
    const int bh = blockIdx.y;
    const int b = bh >> 4, h = bh & 15;
    const int l = threadIdx.x & 63, w = threadIdx.x >> 6;
    const int lm = l & 15, g = l >> 4;
    const int qrow = qb * 64 + w * 16 + lm;
    const u16* qp = qf + (((size_t)(b * S_ + qrow)) * 16 + h) * 192 + g * 8;
    bf16x8 qr[6];
#pragma unroll
    for (int c = 0; c < 6; ++c) qr[c] = *(const bf16x8*)(qp + c * 32);
    f32x4 o[8] = {};
    float mrow[4] = {-1e30f, -1e30f, -1e30f, -1e30f};
    float lrow[4] = {0.f, 0.f, 0.f, 0.f};
    const u16* kb0 = kfs + (size_t)bh * (S_ * 192);
    const u16* vb0 = vfs + (size_t)bh * (S_ * 128);
    const float scale = 0.07216878364870322f;   // 1/sqrt(192)
    for (int kt = 0; kt <= qb; ++kt) {
        const u16* kc = kb0 + (size_t)kt * 12288;
        const u16* vc = vb0 + (size_t)kt * 8192;
#pragma unroll
        for (int i = 0; i < 6; ++i) {
            int c = w + i * 4;
            gld_lds16(kc + c * 512 + l * 8, &Ks[c * 512]);
        }
#pragma unroll
        for (int i = 0; i < 4; ++i) {
            int c = w + i * 4;
            gld_lds16(vc + c * 512 + l * 8, &Vs[c * 512]);
        }
        __syncthreads();
        f32x4 sc[4] = {};
#pragma unroll
        for (int nf = 0; nf < 4; ++nf) {
            int key = nf * 16 + lm;
            int kswz = (key & 7) << 4;
#pragma unroll
            for (int c = 0; c < 6; ++c) {
                int byte = (key * 384 + (c * 32 + g * 8) * 2) ^ kswz;
                bf16x8 kv = *(const bf16x8*)((const char*)Ks + byte);
                sc[nf] = __builtin_amdgcn_mfma_f32_16x16x32_bf16(qr[c], kv, sc[nf], 0, 0, 0);
            }
        }
#pragma unroll
        for (int j = 0; j < 4; ++j) {
            const int q_g = qb * 64 + w * 16 + g * 4 + j;
            float mx = -1e30f;
#pragma unroll
            for (int nf = 0; nf < 4; ++nf) {
                int key_g = kt * 64 + nf * 16 + lm;
                float v = sc[nf][j] * scale;
                v = (key_g > q_g) ? -1e30f : v;
                sc[nf][j] = v;
                mx = fmaxf(mx, v);
            }
            mx = fmaxf(mx, __shfl_xor(mx, 1));
            mx = fmaxf(mx, __shfl_xor(mx, 2));
            mx = fmaxf(mx, __shfl_xor(mx, 4));
            mx = fmaxf(mx, __shfl_xor(mx, 8));
            float newm = fmaxf(mrow[j], mx);
            float fac = __expf(mrow[j] - newm);
            mrow[j] = newm;
            float rs = 0.f;
            u16 pb[4];
#pragma unroll
            for (int nf = 0; nf < 4; ++nf) {
                float pv = __expf(sc[nf][j] - newm);
                rs += pv;
                pb[nf] = f32_bf16(pv);
            }
            rs += __shfl_xor(rs, 1);
            rs += __shfl_xor(rs, 2);
            rs += __shfl_xor(rs, 4);
            rs += __shfl_xor(rs, 8);
            lrow[j] = lrow[j] * fac + rs;
#pragma unroll
            for (int n = 0; n < 8; ++n) o[n][j] *= fac;
            int row = g * 4 + j;
            int rswz = (row & 7) << 4;
#pragma unroll
            for (int nf = 0; nf < 4; ++nf) {
                int byte = (row * 128 + (nf * 16 + lm) * 2) ^ rswz;
                *(u16*)((char*)&Ps[w][0] + byte) = pb[nf];
            }
        }
#pragma unroll
        for (int kc2 = 0; kc2 < 2; ++kc2) {
            int pbyte = (lm * 128 + (kc2 * 32 + g * 8) * 2) ^ ((lm & 7) << 4);
            bf16x8 pa = *(const bf16x8*)((const char*)&Ps[w][0] + pbyte);
#pragma unroll
            for (int n = 0; n < 8; ++n) {
                int dv = n * 16 + lm;
                int vbyte = (dv * 128 + (kc2 * 32 + g * 8) * 2) ^ ((dv & 7) << 4);
                bf16x8 vv = *(const bf16x8*)((const char*)Vs + vbyte);
                o[n] = __builtin_amdgcn_mfma_f32_16x16x32_bf16(pa, vv, o[n], 0, 0, 0);
            }
        }
        __syncthreads();
    }
#pragma unroll
    for (int j = 0; j < 4; ++j) {
        float inv = 1.f / lrow[j];
        int s = qb * 64 + w * 16 + g * 4 + j;
        size_t base = ((size_t)(b * S_ + s)) * (H_ * 128) + h * 128;
#pragma unroll
        for (int n = 0; n < 8; ++n)
            attn[base + n * 16 + lm] = f32_bf16(o[n][j] * inv);
    }
}

extern "C" void kernel_launch(void* const* d_in, const int* in_sizes, int n_in,
                              void* d_out, int out_size, void* d_ws, size_t ws_size,
                              hipStream_t stream) {
    (void)in_sizes; (void)n_in;
    const float* inputs = (const float*)d_in[0];
    const int*   pos    = (const int*)d_in[2];
    const float* pre_s  = (const float*)d_in[3];
    const float* post_s = (const float*)d_in[4];
    const float* q_s    = (const float*)d_in[5];
    const float* kv_s   = (const float*)d_in[6];
    const float* wq_a   = (const float*)d_in[7];
    const float* wq_b   = (const float*)d_in[8];
    const float* wkv_a  = (const float*)d_in[9];
    const float* wkv_b  = (const float*)d_in[10];
    const float* wo_at  = (const float*)d_in[11];
    const float* wi0    = (const float*)d_in[12];
    const float* wi1    = (const float*)d_in[13];
    const float* wom    = (const float*)d_in[14];
    float* out = (float*)d_out;

    char* p = (char*)d_ws;
    auto alloc = [&](size_t n) { char* r = p; p += (n + 255) & ~(size_t)255; return r; };
    u16* slotA = (u16*)alloc((size_t)TOK * 3072 * 2);       // lnx -> qtmp -> act chunk (50.3 MB)
    u16* slotC = (u16*)alloc((size_t)TOK * 2048 * 2);       // q_c -> attnb -> hidden  (33.6 MB)
    u16* slotD = (u16*)alloc((size_t)64 * S_ * 192 * 2);    // kfb -> wi0_t            (50.3 MB)
    u16* slotE = (u16*)alloc((size_t)64 * S_ * 128 * 2);    // vfb -> wi1_t            (33.6 MB)
    u16* slotF = (u16*)alloc((size_t)TOK * 2048 * 2);       // interm bf16             (33.6 MB)
    u16* slotG = (u16*)alloc((size_t)8192 * 2048 * 2);      // rotating weight         (33.6 MB)
    u16* slotH = (u16*)alloc((size_t)2048 * 4096 * 2);      // kvtmp / kvu chunk       (16.8 MB)
    u16* c_kv  = (u16*)alloc((size_t)TOK * 512 * 2);        // (8.4 MB)
    u16* krope = (u16*)alloc((size_t)TOK * 64 * 2);         // (1.0 MB)
    if ((size_t)(p - (char*)d_ws) > ws_size) {
        fill_sentinel<<<(out_size + 255) / 256, 256, 0, stream>>>(out, out_size);
        return;
    }

    // pre-LN
    rmsnorm_f32<<<TOK, 256, 0, stream>>>(inputs, pre_s, slotA, 2048);
    // q_a: lnx @ wq_a -> qa (bf16), rmsnorm in place -> q_c
    transpose_f32_bf16<<<dim3(48, 64), 256, 0, stream>>>(wq_a, slotG, 2048, 1536, 1536);
    gemm_bt<0><<<dim3(12, 64), 256, 0, stream>>>(slotA, slotG, slotC, nullptr, TOK, 1536, 2048);
    rmsnorm_bf16<<<TOK, 256, 0, stream>>>(slotC, q_s, slotC, 1536);
    // kv_a: lnx @ wkv_a -> kvtmp, post -> c_kv + krope
    transpose_f32_bf16<<<dim3(20, 64), 256, 0, stream>>>(wkv_a, slotG, 2048, 576, 640);
    gemm_bt<0><<<dim3(5, 64), 256, 0, stream>>>(slotA, slotG, slotH, nullptr, TOK, 640, 2048);
    kv_post<<<TOK, 128, 0, stream>>>(slotH, kv_s, pos, c_kv, krope);
    // q_b: q_c @ wq_b -> qtmp [tok,16,192], rope in place
    transpose_f32_bf16<<<dim3(96, 48), 256, 0, stream>>>(wq_b, slotG, 1536, 3072, 3072);
    gemm_bt<0><<<dim3(24, 64), 256, 0, stream>>>(slotC, slotG, slotA, nullptr, TOK, 3072, 1536);
    q_rope_inplace<<<dim3(TOK, 16), 64, 0, stream>>>(slotA, pos);
    // kv_b chunked: c_kv @ wkv_b -> kvu chunk -> swizzled kfb/vfb
    transpose_f32_bf16<<<dim3(128, 16), 256, 0, stream>>>(wkv_b, slotG, 512, 4096, 4096);
    for (int ch = 0; ch < 4; ++ch) {
        int t0 = ch * 2048;
        gemm_bt<0><<<dim3(32, 16), 256, 0, stream>>>(c_kv + (size_t)t0 * 512, slotG, slotH, nullptr, 2048, 4096, 512);
        kv_build<<<dim3(2048, 16), 320, 0, stream>>>(slotH, krope, slotD, slotE, t0);
    }
    // attention
    attn_fwd<<<dim3(32, 64), 256, 0, stream>>>(slotA, slotD, slotE, slotC);
    // wo_attn + residual -> interm (bf16)
    transpose_f32_bf16<<<dim3(64, 64), 256, 0, stream>>>(wo_at, slotG, 2048, 2048, 2048);
    gemm_bt<1><<<dim3(16, 64), 256, 0, stream>>>(slotC, slotG, slotF, inputs, TOK, 2048, 2048);
    // post-LN
    rmsnorm_bf16<<<TOK, 256, 0, stream>>>(slotF, post_s, slotC, 2048);
    // MLP chunked
    transpose_f32_bf16<<<dim3(256, 64), 256, 0, stream>>>(wi0, slotD, 2048, 8192, 8192);
    transpose_f32_bf16<<<dim3(256, 64), 256, 0, stream>>>(wi1, slotE, 2048, 8192, 8192);
    transpose_f32_bf16<<<dim3(64, 256), 256, 0, stream>>>(wom, slotG, 8192, 2048, 2048);
    for (int ch = 0; ch < 4; ++ch) {
        int t0 = ch * 2048;
        gemm_mlp<<<dim3(64, 16), 256, 0, stream>>>(slotC + (size_t)t0 * 2048, slotD, slotE, slotA, 2048, 8192, 2048);
        gemm_bt<2><<<dim3(16, 16), 256, 0, stream>>>(slotA, slotG, out + (size_t)t0 * 2048, slotF + (size_t)t0 * 2048, 2048, 2048, 8192);
    }
}

// Round 3
// 1652.189 us; speedup vs baseline: 1.4459x; 1.4459x over previous
//
#include <hip/hip_runtime.h>
#include <stdint.h>

typedef unsigned short u16;
typedef __bf16 bf16x8 __attribute__((ext_vector_type(8)));
typedef float f32x4 __attribute__((ext_vector_type(4)));

#define B_ 4
#define S_ 2048
#define H_ 16
#define TOK (B_*S_)
#define MFMA_B16 __builtin_amdgcn_mfma_f32_16x16x32_bf16

__device__ __forceinline__ u16 f32_bf16(float f) {
    union { float f; unsigned int u; } x; x.f = f;
    return (u16)((x.u + 0x7fffu + ((x.u >> 16) & 1u)) >> 16);
}
__device__ __forceinline__ float bf2f(u16 v) {
    union { unsigned int u; float f; } x; x.u = ((unsigned int)v) << 16; return x.f;
}
__device__ __forceinline__ void gld_lds16(const u16* g, u16* lds) {
    __builtin_amdgcn_global_load_lds(
        (const __attribute__((address_space(1))) unsigned int*)g,
        (__attribute__((address_space(3))) unsigned int*)lds, 16, 0, 0);
}

__global__ void fill_sentinel(float* o, int n) {
    int i = blockIdx.x * 256 + threadIdx.x;
    if (i < n) o[i] = 12345.0f;
}

// ---------------- weight transpose + f32->bf16: in [K,N] f32 -> out [Npad,K] bf16 ----------------
__global__ __launch_bounds__(256) void transpose_f32_bf16(const float* __restrict__ in, u16* __restrict__ out,
                                                          int K, int N, int Npad) {
    __shared__ float t[32][33];
    int nb = blockIdx.x * 32, kb = blockIdx.y * 32;
    int c = threadIdx.x & 31, r = threadIdx.x >> 5;
#pragma unroll
    for (int i = 0; i < 4; ++i) {
        int kk = kb + r + i * 8, nn = nb + c;
        t[r + i * 8][c] = (kk < K && nn < N) ? in[(size_t)kk * N + nn] : 0.f;
    }
    __syncthreads();
#pragma unroll
    for (int i = 0; i < 4; ++i) {
        int no = nb + r + i * 8, ko = kb + c;
        if (no < Npad && ko < K) out[(size_t)no * K + ko] = f32_bf16(t[c][r + i * 8]);
    }
}

// ---------------- rmsnorm: f32 in -> bf16 out ----------------
__global__ __launch_bounds__(256) void rmsnorm_f32(const float* __restrict__ in, const float* __restrict__ sc,
                                                   u16* __restrict__ out, int N) {
    int row = blockIdx.x;
    const float* x = in + (size_t)row * N;
    float ss = 0.f;
    for (int c = threadIdx.x * 4; c < N; c += 1024) {
        float4 v = *(const float4*)(x + c);
        ss += v.x * v.x + v.y * v.y + v.z * v.z + v.w * v.w;
    }
#pragma unroll
    for (int off = 32; off; off >>= 1) ss += __shfl_down(ss, off);
    __shared__ float red[4];
    if ((threadIdx.x & 63) == 0) red[threadIdx.x >> 6] = ss;
    __syncthreads();
    float rs = rsqrtf((red[0] + red[1] + red[2] + red[3]) / (float)N + 1e-6f);
    for (int c = threadIdx.x * 4; c < N; c += 1024) {
        float4 v = *(const float4*)(x + c);
        float4 s4 = *(const float4*)(sc + c);
        ushort4 ov;
        ov.x = f32_bf16(v.x * rs * s4.x);
        ov.y = f32_bf16(v.y * rs * s4.y);
        ov.z = f32_bf16(v.z * rs * s4.z);
        ov.w = f32_bf16(v.w * rs * s4.w);
        *(ushort4*)&out[(size_t)row * N + c] = ov;
    }
}

// ---------------- rmsnorm: bf16 in -> bf16 out (in-place safe) ----------------
__global__ __launch_bounds__(256) void rmsnorm_bf16(const u16* __restrict__ in, const float* __restrict__ sc,
                                                    u16* __restrict__ out, int N) {
    int row = blockIdx.x;
    const u16* x = in + (size_t)row * N;
    float ss = 0.f;
    for (int c = threadIdx.x * 8; c < N; c += 2048) {
        ushort4 v0 = *(const ushort4*)(x + c);
        ushort4 v1 = *(const ushort4*)(x + c + 4);
        float f0 = bf2f(v0.x), f1 = bf2f(v0.y), f2 = bf2f(v0.z), f3 = bf2f(v0.w);
        float f4 = bf2f(v1.x), f5 = bf2f(v1.y), f6 = bf2f(v1.z), f7 = bf2f(v1.w);
        ss += f0*f0 + f1*f1 + f2*f2 + f3*f3 + f4*f4 + f5*f5 + f6*f6 + f7*f7;
    }
#pragma unroll
    for (int off = 32; off; off >>= 1) ss += __shfl_down(ss, off);
    __shared__ float red[4];
    if ((threadIdx.x & 63) == 0) red[threadIdx.x >> 6] = ss;
    __syncthreads();
    float rs = rsqrtf((red[0] + red[1] + red[2] + red[3]) / (float)N + 1e-6f);
    for (int c = threadIdx.x * 8; c < N; c += 2048) {
        ushort4 v0 = *(const ushort4*)(x + c);
        ushort4 v1 = *(const ushort4*)(x + c + 4);
        ushort4 o0, o1;
        o0.x = f32_bf16(bf2f(v0.x) * rs * sc[c + 0]);
        o0.y = f32_bf16(bf2f(v0.y) * rs * sc[c + 1]);
        o0.z = f32_bf16(bf2f(v0.z) * rs * sc[c + 2]);
        o0.w = f32_bf16(bf2f(v0.w) * rs * sc[c + 3]);
        o1.x = f32_bf16(bf2f(v1.x) * rs * sc[c + 4]);
        o1.y = f32_bf16(bf2f(v1.y) * rs * sc[c + 5]);
        o1.z = f32_bf16(bf2f(v1.z) * rs * sc[c + 6]);
        o1.w = f32_bf16(bf2f(v1.w) * rs * sc[c + 7]);
        *(ushort4*)&out[(size_t)row * N + c] = o0;
        *(ushort4*)&out[(size_t)row * N + c + 4] = o1;
    }
}

// ---------------- kv post ----------------
__global__ __launch_bounds__(128) void kv_post(const u16* __restrict__ kv, const float* __restrict__ scale,
                                               const int* __restrict__ pos, u16* __restrict__ ckv,
                                               u16* __restrict__ kr) {
    int row = blockIdx.x;
    const u16* x = kv + (size_t)row * 640;
    int c = threadIdx.x * 4;
    ushort4 v = *(const ushort4*)(x + c);
    float f0 = bf2f(v.x), f1 = bf2f(v.y), f2 = bf2f(v.z), f3 = bf2f(v.w);
    float ss = f0*f0 + f1*f1 + f2*f2 + f3*f3;
#pragma unroll
    for (int off = 32; off; off >>= 1) ss += __shfl_down(ss, off);
    __shared__ float red[2];
    if ((threadIdx.x & 63) == 0) red[threadIdx.x >> 6] = ss;
    __syncthreads();
    float rs = rsqrtf((red[0] + red[1]) * (1.f / 512.f) + 1e-6f);
    float4 s4 = *(const float4*)(scale + c);
    ushort4 ov;
    ov.x = f32_bf16(f0 * rs * s4.x);
    ov.y = f32_bf16(f1 * rs * s4.y);
    ov.z = f32_bf16(f2 * rs * s4.z);
    ov.w = f32_bf16(f3 * rs * s4.w);
    *(ushort4*)&ckv[(size_t)row * 512 + c] = ov;
    if (threadIdx.x < 32) {
        int i = threadIdx.x;
        float x1 = bf2f(x[512 + i]), x2 = bf2f(x[544 + i]);
        float inv = expf(-(float)(2 * i) * (1.f / 64.f) * 9.2103403719761836f);
        float ang = (float)pos[row] * inv;
        float sn, cs; sincosf(ang, &sn, &cs);
        kr[(size_t)row * 64 + i]      = f32_bf16(x1 * cs - x2 * sn);
        kr[(size_t)row * 64 + 32 + i] = f32_bf16(x2 * cs + x1 * sn);
    }
}

// ---------------- q rope in-place ----------------
__global__ __launch_bounds__(64) void q_rope_inplace(u16* __restrict__ q, const int* __restrict__ pos) {
    int token = blockIdx.x, h = blockIdx.y;
    u16* p = q + ((size_t)token * 16 + h) * 192;
    int t = threadIdx.x, i = t & 31;
    float x1 = bf2f(p[128 + i]), x2 = bf2f(p[160 + i]);
    float inv = expf(-(float)(2 * i) * (1.f / 64.f) * 9.2103403719761836f);
    float ang = (float)pos[token] * inv;
    float sn, cs; sincosf(ang, &sn, &cs);
    float val = (t < 32) ? (x1 * cs - x2 * sn) : (x2 * cs + x1 * sn);
    p[128 + t] = f32_bf16(val);
}

// ---------------- kv build: bf16 kvu chunk -> swizzled K tiles / V^T tiles ----------------
__global__ __launch_bounds__(320) void kv_build(const u16* __restrict__ kvu, const u16* __restrict__ kr,
                                                u16* __restrict__ kf, u16* __restrict__ vf, int tok0) {
    int local = blockIdx.x, h = blockIdx.y;
    int token = tok0 + local;
    int b = token >> 11, s = token & 2047;
    int bh = b * 16 + h;
    int tile = s >> 6, ki = s & 63;
    const u16* u = kvu + ((size_t)local * 16 + h) * 256;
    int t = threadIdx.x;
    if (t < 192) {
        u16 val = (t < 128) ? u[t] : kr[(size_t)token * 64 + (t - 128)];
        int byte = (ki * 384 + t * 2) ^ ((ki & 7) << 4);
        kf[(size_t)bh * (S_ * 192) + (size_t)tile * 12288 + (byte >> 1)] = val;
    } else {
        int dv = t - 192;
        u16 val = u[128 + dv];
        int byte = (dv * 128 + ki * 2) ^ ((dv & 7) << 4);
        vf[(size_t)bh * (S_ * 128) + (size_t)tile * 8192 + (byte >> 1)] = val;
    }
}

// ---------------- 128-tile GEMM (m97 structure), bf16 out; for shapes not /256 ----------------
__global__ __launch_bounds__(256) void gemm128(const u16* __restrict__ A, const u16* __restrict__ Bt,
                                               u16* __restrict__ C, int M, int N, int K) {
    __shared__ u16 As[128 * 32];
    __shared__ u16 Bs[128 * 32];
    const int l = threadIdx.x & 63, w = threadIdx.x >> 6;
    const int wr = w >> 1, wc = w & 1;
    const int m0 = blockIdx.y * 128, n0 = blockIdx.x * 128;
    const int lm = l & 15, lg = l >> 4;
    const int srow = l >> 2, sk = (l & 3) * 8;
    f32x4 acc[4][4] = {};
    for (int k0 = 0; k0 < K; k0 += 32) {
#pragma unroll
        for (int i = 0; i < 2; ++i) {
            int c = w * 2 + i;
            gld_lds16(A  + (size_t)(m0 + c * 16 + srow) * K + k0 + sk, &As[c * 512]);
            gld_lds16(Bt + (size_t)(n0 + c * 16 + srow) * K + k0 + sk, &Bs[c * 512]);
        }
        __syncthreads();
        bf16x8 a[4], b[4];
#pragma unroll
        for (int m = 0; m < 4; ++m) a[m] = *(const bf16x8*)&As[(wr * 64 + m * 16 + lm) * 32 + lg * 8];
#pragma unroll
        for (int n = 0; n < 4; ++n) b[n] = *(const bf16x8*)&Bs[(wc * 64 + n * 16 + lm) * 32 + lg * 8];
#pragma unroll
        for (int m = 0; m < 4; ++m)
#pragma unroll
            for (int n = 0; n < 4; ++n)
                acc[m][n] = MFMA_B16(a[m], b[n], acc[m][n], 0, 0, 0);
        __syncthreads();
    }
#pragma unroll
    for (int m = 0; m < 4; ++m)
#pragma unroll
        for (int j = 0; j < 4; ++j) {
            int row = m0 + wr * 64 + m * 16 + lg * 4 + j;
            size_t base = (size_t)row * N + n0 + wc * 64;
#pragma unroll
            for (int n = 0; n < 4; ++n)
                C[base + n * 16 + lm] = f32_bf16(acc[m][n][j]);
        }
}

// ---------------- 256-tile deep-pipelined GEMM ----------------
// EPI 0: bf16 out. EPI 1: f32 out = acc + f32 resid (resid may alias out). EPI 2: bf16 out = silu(resid)*acc, resid bf16 (may alias out).
template<int EPI>
__global__ __launch_bounds__(512, 2) void gemm256(const u16* __restrict__ A, const u16* __restrict__ Bt,
                                                  void* __restrict__ Cv, const void* __restrict__ Rv,
                                                  int M, int N, int K) {
    __shared__ u16 lds[65536];            // 128 KiB: 2 bufs x (A 32KB | B 32KB)
    char* ldsb = (char*)lds;
    const int tid = threadIdx.x;
    const int l = tid & 63, w = tid >> 6;
    const int wr = w >> 2, wcn = w & 3;   // 2 (M) x 4 (N) waves
    const int lm = l & 15, lg = l >> 4;
    const int m0 = blockIdx.y * 256, n0 = blockIdx.x * 256;

    // staging: per thread 2 loads per half-tile; linear LDS dest P, inverse-swizzled source
    int srow[2], scb[2];
#pragma unroll
    for (int ld = 0; ld < 2; ++ld) {
        int P = tid * 16 + ld * 8192;                 // within 16KB half
        int L = P ^ (((P >> 7) & 7) << 4);            // involution (bits 4-6)
        srow[ld] = L >> 7; scb[ld] = L & 127;
    }
    const u16* Ablk = A + (size_t)m0 * K;
    const u16* Bblk = Bt + (size_t)n0 * K;

    f32x4 acc[8][4] = {};

    auto stage = [&](const u16* gp, int h, int kt, int db, int streamoff) {
#pragma unroll
        for (int ld = 0; ld < 2; ++ld) {
            const u16* src = gp + (size_t)(h * 128 + srow[ld]) * K + kt * 64 + (scb[ld] >> 1);
            u16* dst = (u16*)(ldsb + db * 65536 + streamoff + h * 16384 + w * 1024 + ld * 8192);
            gld_lds16(src, dst);
        }
    };
    auto readA = [&](int db, int fm, int ks) -> bf16x8 {
        int row = wr * 128 + fm * 16 + lm;
        int cb = lg * 16 + ks * 64;
        return *(const bf16x8*)(ldsb + db * 65536 + row * 128 + (cb ^ ((row & 7) << 4)));
    };
    auto readB = [&](int db, int fn, int ks) -> bf16x8 {
        int row = wcn * 64 + fn * 16 + lm;
        int cb = lg * 16 + ks * 64;
        return *(const bf16x8*)(ldsb + db * 65536 + 32768 + row * 128 + (cb ^ ((row & 7) << 4)));
    };

    const int ntile = K >> 6;
    // prologue: stage tile 0 -> buf 0
#pragma unroll
    for (int h = 0; h < 2; ++h) stage(Ablk, h, 0, 0, 0);
#pragma unroll
    for (int h = 0; h < 2; ++h) stage(Bblk, h, 0, 0, 32768);
    asm volatile("s_waitcnt vmcnt(0)" ::: "memory");
    __builtin_amdgcn_s_barrier();

    for (int t = 0; t < ntile; ++t) {
        const int db = t & 1;
        bf16x8 bfr[4][2];
        // ---- phase 0: read B frags + A frags fm 0,1; issue ALL stages for tile t+1 ----
        bf16x8 a0 = readA(db, 0, 0), a1 = readA(db, 0, 1);
        bf16x8 a2 = readA(db, 1, 0), a3 = readA(db, 1, 1);
#pragma unroll
        for (int fn = 0; fn < 4; ++fn) { bfr[fn][0] = readB(db, fn, 0); bfr[fn][1] = readB(db, fn, 1); }
        if (t + 1 < ntile) {
#pragma unroll
            for (int h = 0; h < 2; ++h) stage(Ablk, h, t + 1, db ^ 1, 0);
#pragma unroll
            for (int h = 0; h < 2; ++h) stage(Bblk, h, t + 1, db ^ 1, 32768);
        }
        __builtin_amdgcn_s_barrier();
        asm volatile("s_waitcnt lgkmcnt(0)" ::: "memory");
        __builtin_amdgcn_sched_barrier(0);
        __builtin_amdgcn_s_setprio(1);
#pragma unroll
        for (int fn = 0; fn < 4; ++fn) {
            acc[0][fn] = MFMA_B16(a0, bfr[fn][0], acc[0][fn], 0, 0, 0);
            acc[0][fn] = MFMA_B16(a1, bfr[fn][1], acc[0][fn], 0, 0, 0);
            acc[1][fn] = MFMA_B16(a2, bfr[fn][0], acc[1][fn], 0, 0, 0);
            acc[1][fn] = MFMA_B16(a3, bfr[fn][1], acc[1][fn], 0, 0, 0);
        }
        __builtin_amdgcn_s_setprio(0);
        __builtin_amdgcn_s_barrier();
        // ---- phases 1..3: A frags fm {2p,2p+1} ----
#pragma unroll
        for (int p = 1; p < 4; ++p) {
            a0 = readA(db, 2 * p, 0);     a1 = readA(db, 2 * p, 1);
            a2 = readA(db, 2 * p + 1, 0); a3 = readA(db, 2 * p + 1, 1);
            if (p == 3) asm volatile("s_waitcnt vmcnt(0)" ::: "memory");   // per-wave drain; ~3 phases elapsed since issue
            __builtin_amdgcn_s_barrier();
            asm volatile("s_waitcnt lgkmcnt(0)" ::: "memory");
            __builtin_amdgcn_sched_barrier(0);
            __builtin_amdgcn_s_setprio(1);
#pragma unroll
            for (int fn = 0; fn < 4; ++fn) {
                acc[2*p][fn]   = MFMA_B16(a0, bfr[fn][0], acc[2*p][fn], 0, 0, 0);
                acc[2*p][fn]   = MFMA_B16(a1, bfr[fn][1], acc[2*p][fn], 0, 0, 0);
                acc[2*p+1][fn] = MFMA_B16(a2, bfr[fn][0], acc[2*p+1][fn], 0, 0, 0);
                acc[2*p+1][fn] = MFMA_B16(a3, bfr[fn][1], acc[2*p+1][fn], 0, 0, 0);
            }
            __builtin_amdgcn_s_setprio(0);
            __builtin_amdgcn_s_barrier();
        }
    }
    // ---- epilogue ----
#pragma unroll
    for (int fm = 0; fm < 8; ++fm)
#pragma unroll
        for (int j = 0; j < 4; ++j) {
            int row = m0 + wr * 128 + fm * 16 + lg * 4 + j;
            size_t base = (size_t)row * N + n0 + wcn * 64;
#pragma unroll
            for (int fn = 0; fn < 4; ++fn) {
                size_t idx = base + fn * 16 + lm;
                float v = acc[fm][fn][j];
                if (EPI == 0) {
                    ((u16*)Cv)[idx] = f32_bf16(v);
                } else if (EPI == 1) {
                    ((float*)Cv)[idx] = v + ((const float*)Rv)[idx];
                } else {
                    float x0 = bf2f(((const u16*)Rv)[idx]);
                    float sl = x0 / (1.f + expf(-x0));
                    ((u16*)Cv)[idx] = f32_bf16(sl * v);
                }
            }
        }
}

// ---------------- flash attention, causal, paired q-tiles for load balance ----------------
__global__ __launch_bounds__(256) void attn_fwd(const u16* __restrict__ qf, const u16* __restrict__ kfs,
                                                const u16* __restrict__ vfs, u16* __restrict__ attn) {
    __shared__ u16 Ks[64 * 192];
    __shared__ u16 Vs[128 * 64];
    __shared__ u16 Ps[4][1024];
    const int px = blockIdx.x;     // pair index 0..15
    const int bh = blockIdx.y;
    const int b = bh >> 4, h = bh & 15;
    const int l = threadIdx.x & 63, w = threadIdx.x >> 6;
    const int lm = l & 15, g = l >> 4;
    const u16* kb0 = kfs + (size_t)bh * (S_ * 192);
    const u16* vb0 = vfs + (size_t)bh * (S_ * 128);
    const float scale = 0.07216878364870322f;   // 1/sqrt(192)

    for (int pass = 0; pass < 2; ++pass) {
        const int qb = pass ? (31 - px) : px;
        const int qrow = qb * 64 + w * 16 + lm;
        const u16* qp = qf + (((size_t)(b * S_ + qrow)) * 16 + h) * 192 + g * 8;
        bf16x8 qr[6];
#pragma unroll
        for (int c = 0; c < 6; ++c) qr[c] = *(const bf16x8*)(qp + c * 32);
        f32x4 o[8] = {};
        float mrow[4] = {-1e30f, -1e30f, -1e30f, -1e30f};
        float lrow[4] = {0.f, 0.f, 0.f, 0.f};
        for (int kt = 0; kt <= qb; ++kt) {
            const u16* kc = kb0 + (size_t)kt * 12288;
            const u16* vc = vb0 + (size_t)kt * 8192;
#pragma unroll
            for (int i = 0; i < 6; ++i) {
                int c = w + i * 4;
                gld_lds16(kc + c * 512 + l * 8, &Ks[c * 512]);
            }
#pragma unroll
            for (int i = 0; i < 4; ++i) {
                int c = w + i * 4;
                gld_lds16(vc + c * 512 + l * 8, &Vs[c * 512]);
            }
            __syncthreads();
            f32x4 sc[4] = {};
#pragma unroll
            for (int nf = 0; nf < 4; ++nf) {
                int key = nf * 16 + lm;
                int kswz = (key & 7) << 4;
#pragma unroll
                for (int c = 0; c < 6; ++c) {
                    int byte = (key * 384 + (c * 32 + g * 8) * 2) ^ kswz;
                    bf16x8 kv = *(const bf16x8*)((const char*)Ks + byte);
                    sc[nf] = MFMA_B16(qr[c], kv, sc[nf], 0, 0, 0);
                }
            }
#pragma unroll
            for (int j = 0; j < 4; ++j) {
                const int q_g = qb * 64 + w * 16 + g * 4 + j;
                float mx = -1e30f;
#pragma unroll
                for (int nf = 0; nf < 4; ++nf) {
                    int key_g = kt * 64 + nf * 16 + lm;
                    float v = sc[nf][j] * scale;
                    v = (key_g > q_g) ? -1e30f : v;
                    sc[nf][j] = v;
                    mx = fmaxf(mx, v);
                }
                mx = fmaxf(mx, __shfl_xor(mx, 1));
                mx = fmaxf(mx, __shfl_xor(mx, 2));
                mx = fmaxf(mx, __shfl_xor(mx, 4));
                mx = fmaxf(mx, __shfl_xor(mx, 8));
                float newm = fmaxf(mrow[j], mx);
                float fac = __expf(mrow[j] - newm);
                mrow[j] = newm;
                float rs = 0.f;
                u16 pb[4];
#pragma unroll
                for (int nf = 0; nf < 4; ++nf) {
                    float pv = __expf(sc[nf][j] - newm);
                    rs += pv;
                    pb[nf] = f32_bf16(pv);
                }
                rs += __shfl_xor(rs, 1);
                rs += __shfl_xor(rs, 2);
                rs += __shfl_xor(rs, 4);
                rs += __shfl_xor(rs, 8);
                lrow[j] = lrow[j] * fac + rs;
#pragma unroll
                for (int n = 0; n < 8; ++n) o[n][j] *= fac;
                int row = g * 4 + j;
                int rswz = (row & 7) << 4;
#pragma unroll
                for (int nf = 0; nf < 4; ++nf) {
                    int byte = (row * 128 + (nf * 16 + lm) * 2) ^ rswz;
                    *(u16*)((char*)&Ps[w][0] + byte) = pb[nf];
                }
            }
#pragma unroll
            for (int kc2 = 0; kc2 < 2; ++kc2) {
                int pbyte = (lm * 128 + (kc2 * 32 + g * 8) * 2) ^ ((lm & 7) << 4);
                bf16x8 pa = *(const bf16x8*)((const char*)&Ps[w][0] + pbyte);
#pragma unroll
                for (int n = 0; n < 8; ++n) {
                    int dv = n * 16 + lm;
                    int vbyte = (dv * 128 + (kc2 * 32 + g * 8) * 2) ^ ((dv & 7) << 4);
                    bf16x8 vv = *(const bf16x8*)((const char*)Vs + vbyte);
                    o[n] = MFMA_B16(pa, vv, o[n], 0, 0, 0);
                }
            }
            __syncthreads();
        }
#pragma unroll
        for (int j = 0; j < 4; ++j) {
            float inv = 1.f / lrow[j];
            int s = qb * 64 + w * 16 + g * 4 + j;
            size_t base = ((size_t)(b * S_ + s)) * (H_ * 128) + h * 128;
#pragma unroll
            for (int n = 0; n < 8; ++n)
                attn[base + n * 16 + lm] = f32_bf16(o[n][j] * inv);
        }
    }
}

extern "C" void kernel_launch(void* const* d_in, const int* in_sizes, int n_in,
                              void* d_out, int out_size, void* d_ws, size_t ws_size,
                              hipStream_t stream) {
    (void)in_sizes; (void)n_in;
    const float* inputs = (const float*)d_in[0];
    const int*   pos    = (const int*)d_in[2];
    const float* pre_s  = (const float*)d_in[3];
    const float* post_s = (const float*)d_in[4];
    const float* q_s    = (const float*)d_in[5];
    const float* kv_s   = (const float*)d_in[6];
    const float* wq_a   = (const float*)d_in[7];
    const float* wq_b   = (const float*)d_in[8];
    const float* wkv_a  = (const float*)d_in[9];
    const float* wkv_b  = (const float*)d_in[10];
    const float* wo_at  = (const float*)d_in[11];
    const float* wi0    = (const float*)d_in[12];
    const float* wi1    = (const float*)d_in[13];
    const float* wom    = (const float*)d_in[14];
    float* out = (float*)d_out;

    char* p = (char*)d_ws;
    auto alloc = [&](size_t n) { char* r = p; p += (n + 255) & ~(size_t)255; return r; };
    char* R1   = alloc((size_t)134217728);       // mega region
    u16* vf    = (u16*)alloc((size_t)33554432);
    u16* aslot = (u16*)alloc((size_t)33554432);  // attnb -> hidden
    u16* wslot = (u16*)alloc((size_t)33554432);  // rotating transposed weight
    u16* ckv   = (u16*)alloc((size_t)8388608);
    u16* krope = (u16*)alloc((size_t)1048576);
    if ((size_t)(p - (char*)d_ws) > ws_size) {
        fill_sentinel<<<(out_size + 255) / 256, 256, 0, stream>>>(out, out_size);
        return;
    }
    // R1 overlays (lifetimes disjoint as scheduled below)
    u16* kf    = (u16*)R1;                      // 50.33 MB  [kv_build -> attn]
    u16* q_c   = (u16*)R1;                      // 25.17 MB  [q_a -> q_b]
    u16* kvtmp = (u16*)(R1 + 25165824);         // 10.49 MB  [kv_a -> kv_post]
    u16* q     = (u16*)(R1 + 50331648);         // 50.33 MB  [q_b -> attn]
    u16* lnx   = (u16*)(R1 + 100663296);        // 33.55 MB  [preLN -> kv_a]
    u16* kvu   = (u16*)(R1 + 100663296);        // 33.55 MB  [kv_b chunk -> kv_build]
    u16* X     = (u16*)R1;                      // 134.2 MB  [MLP]

    // pre-LN
    rmsnorm_f32<<<TOK, 256, 0, stream>>>(inputs, pre_s, lnx, 2048);
    // q_a: lnx @ wq_a^T -> q_c, rmsnorm in place
    transpose_f32_bf16<<<dim3(48, 64), 256, 0, stream>>>(wq_a, wslot, 2048, 1536, 1536);
    gemm256<0><<<dim3(6, 32), 512, 0, stream>>>(lnx, wslot, q_c, nullptr, TOK, 1536, 2048);
    rmsnorm_bf16<<<TOK, 256, 0, stream>>>(q_c, q_s, q_c, 1536);
    // kv_a (N=640, 128-tile path)
    transpose_f32_bf16<<<dim3(20, 64), 256, 0, stream>>>(wkv_a, wslot, 2048, 576, 640);
    gemm128<<<dim3(5, 64), 256, 0, stream>>>(lnx, wslot, kvtmp, TOK, 640, 2048);
    kv_post<<<TOK, 128, 0, stream>>>(kvtmp, kv_s, pos, ckv, krope);
    // q_b -> q [tok,16,192], rope in place
    transpose_f32_bf16<<<dim3(96, 48), 256, 0, stream>>>(wq_b, wslot, 1536, 3072, 3072);
    gemm256<0><<<dim3(12, 32), 512, 0, stream>>>(q_c, wslot, q, nullptr, TOK, 3072, 1536);
    q_rope_inplace<<<dim3(TOK, 16), 64, 0, stream>>>(q, pos);
    // kv_b in 2 chunks of M=4096 -> swizzled kf/vf
    transpose_f32_bf16<<<dim3(128, 16), 256, 0, stream>>>(wkv_b, wslot, 512, 4096, 4096);
    for (int ch = 0; ch < 2; ++ch) {
        int t0 = ch * 4096;
        gemm256<0><<<dim3(16, 16), 512, 0, stream>>>(ckv + (size_t)t0 * 512, wslot, kvu, nullptr, 4096, 4096, 512);
        kv_build<<<dim3(4096, 16), 320, 0, stream>>>(kvu, krope, kf, vf, t0);
    }
    // attention (paired q-tiles)
    attn_fwd<<<dim3(16, 64), 256, 0, stream>>>(q, kf, vf, aslot);
    // wo_attn + residual -> d_out (f32 interm)
    transpose_f32_bf16<<<dim3(64, 64), 256, 0, stream>>>(wo_at, wslot, 2048, 2048, 2048);
    gemm256<1><<<dim3(8, 32), 512, 0, stream>>>(aslot, wslot, out, inputs, TOK, 2048, 2048);
    // post-LN: d_out -> hidden
    rmsnorm_f32<<<TOK, 256, 0, stream>>>(out, post_s, aslot, 2048);
    // MLP: X = hidden@wi0; X = silu(X)*(hidden@wi1); out += X@wom
    transpose_f32_bf16<<<dim3(256, 64), 256, 0, stream>>>(wi0, wslot, 2048, 8192, 8192);
    gemm256<0><<<dim3(32, 32), 512, 0, stream>>>(aslot, wslot, X, nullptr, TOK, 8192, 2048);
    transpose_f32_bf16<<<dim3(256, 64), 256, 0, stream>>>(wi1, wslot, 2048, 8192, 8192);
    gemm256<2><<<dim3(32, 32), 512, 0, stream>>>(aslot, wslot, X, X, TOK, 8192, 2048);
    transpose_f32_bf16<<<dim3(64, 256), 256, 0, stream>>>(wom, wslot, 8192, 2048, 2048);
    gemm256<1><<<dim3(8, 32), 512, 0, stream>>>(X, wslot, out, out, TOK, 2048, 8192);
}